// Round 2
// baseline (3715.742 us; speedup 1.0000x reference)
//
#include <hip/hip_runtime.h>
#include <cstdint>
#include <cstddef>

// ---------------------------------------------------------------------------
// MiniGPT forward (L=8, H=8, E=768, FF=3072, V=32000, B=4, T=1024) on gfx950.
// Residual stream fp32; all GEMMs bf16 MFMA (16x16x32) in m97-style NT form.
// This revision: flash attention moved from fp32-VALU to bf16 MFMA
// (QK^T and PV as 16x16x32 MFMA tiles, register-resident online softmax).
// ---------------------------------------------------------------------------

typedef __bf16 bf16_t;
typedef __bf16 bf16x8 __attribute__((ext_vector_type(8)));
typedef __bf16 bf16x4 __attribute__((ext_vector_type(4)));
typedef float  f32x4  __attribute__((ext_vector_type(4)));

#define LNUM 8
#define EMB 768
#define FFDIM 3072
#define HEADS 8
#define HSZ 96
#define VOC 32000
#define SEQ 1024
#define MTOK 4096          // B*T
#define NT500 500          // VOC/64 partial tiles per row

__device__ __forceinline__ void lds16(const void* g, void* l) {
    __builtin_amdgcn_global_load_lds(
        (__attribute__((address_space(1))) void*)(g),
        (__attribute__((address_space(3))) void*)(l), 16, 0, 0);
}

// ---------------------------------------------------------------- casts ----
__global__ __launch_bounds__(256) void cast_bf16_kernel(
    const float* __restrict__ s, bf16_t* __restrict__ d, int n4)
{
    int i = blockIdx.x * 256 + threadIdx.x;
    if (i < n4) {
        float4 v = ((const float4*)s)[i];
        bf16x4 o;
        o[0] = (bf16_t)v.x; o[1] = (bf16_t)v.y;
        o[2] = (bf16_t)v.z; o[3] = (bf16_t)v.w;
        ((bf16x4*)d)[i] = o;
    }
}

// src [K,N] f32 (batched)  ->  dst [N,K] bf16 (batched)
__global__ __launch_bounds__(256) void transpose_cast_kernel(
    const float* __restrict__ src, bf16_t* __restrict__ dst,
    int K, int N, long long sstride, long long dstride)
{
    __shared__ float t[32][33];
    src += (long long)blockIdx.z * sstride;
    dst += (long long)blockIdx.z * dstride;
    int n0 = blockIdx.x * 32, k0 = blockIdx.y * 32;
    int tx = threadIdx.x, ty = threadIdx.y;
    for (int i = ty; i < 32; i += 8)
        t[i][tx] = src[(size_t)(k0 + i) * N + n0 + tx];
    __syncthreads();
    for (int i = ty; i < 32; i += 8)
        dst[(size_t)(n0 + i) * K + k0 + tx] = (bf16_t)t[tx][i];
}

// ---------------------------------------------------------------- embed ----
__global__ __launch_bounds__(256) void embed_kernel(
    const int* __restrict__ idx, const float* __restrict__ tok,
    const float* __restrict__ pos, float* __restrict__ x)
{
    int row = blockIdx.x, tid = threadIdx.x;
    int id = idx[row];
    int t = row & (SEQ - 1);
    const float* te = tok + (size_t)id * EMB;
    const float* pe = pos + (size_t)t * EMB;
    float* xr = x + (size_t)row * EMB;
    xr[tid]       = te[tid]       + pe[tid];
    xr[tid + 256] = te[tid + 256] + pe[tid + 256];
    xr[tid + 512] = te[tid + 512] + pe[tid + 512];
}

// ------------------------------------------------------------- layernorm ----
__global__ __launch_bounds__(256) void ln_kernel(
    const float* __restrict__ x, const float* __restrict__ g,
    const float* __restrict__ bb, bf16_t* __restrict__ out)
{
    int row = blockIdx.x, tid = threadIdx.x;
    const float* xr = x + (size_t)row * EMB;
    float v0 = xr[tid], v1 = xr[tid + 256], v2 = xr[tid + 512];
    float s = v0 + v1 + v2;
    float s2 = v0 * v0 + v1 * v1 + v2 * v2;
#pragma unroll
    for (int off = 32; off >= 1; off >>= 1) {
        s  += __shfl_xor(s, off);
        s2 += __shfl_xor(s2, off);
    }
    __shared__ float red[8];
    int w = tid >> 6;
    if ((tid & 63) == 0) { red[w] = s; red[4 + w] = s2; }
    __syncthreads();
    s  = red[0] + red[1] + red[2] + red[3];
    s2 = red[4] + red[5] + red[6] + red[7];
    float mean = s * (1.0f / EMB);
    float var  = s2 * (1.0f / EMB) - mean * mean;
    float rs = rsqrtf(var + 1e-5f);
    bf16_t* orow = out + (size_t)row * EMB;
    orow[tid]       = (bf16_t)((v0 - mean) * rs * g[tid]       + bb[tid]);
    orow[tid + 256] = (bf16_t)((v1 - mean) * rs * g[tid + 256] + bb[tid + 256]);
    orow[tid + 512] = (bf16_t)((v2 - mean) * rs * g[tid + 512] + bb[tid + 512]);
}

// ------------------------------------------------------------------ GEMM ----
// C[M,N] = A[M,K](bf16) @ B[N,K](bf16)^T  (NT, both K-contiguous).
// 128x128 tile, BK=32, 256 threads = 4 waves (2x2 of 64x64), 16 MFMAs/wave/iter.
// outH!=null: bf16 out (+bias, +gelu). else f32 out (+bias, +residual, +lm partials).
__global__ __launch_bounds__(256) void gemm_nt_kernel(
    const bf16_t* __restrict__ A, const bf16_t* __restrict__ B,
    int N, int K, long long strideBz, long long strideOz,
    const float* __restrict__ bias, const float* __restrict__ resid,
    float* __restrict__ outF, bf16_t* __restrict__ outH, int gelu_flag,
    float* __restrict__ pmaxp, float* __restrict__ psump, int nt500)
{
    __shared__ __align__(16) bf16_t As[128 * 32];
    __shared__ __align__(16) bf16_t Bs[128 * 32];
    int tid = threadIdx.x;
    int m0 = blockIdx.y * 128;
    int n0 = blockIdx.x * 128;
    int z = blockIdx.z;
    B += (long long)z * strideBz;

    int wv = tid >> 6, lane = tid & 63;
    int quad = lane >> 4, l16 = lane & 15;
    int wm = wv >> 1, wn = wv & 1;

    const bf16_t* gA0 = A + (size_t)(m0 + (tid >> 2)) * K + (tid & 3) * 8;
    const bf16_t* gA1 = gA0 + (size_t)64 * K;
    const bf16_t* gB0 = B + (size_t)(n0 + (tid >> 2)) * K + (tid & 3) * 8;
    const bf16_t* gB1 = gB0 + (size_t)64 * K;
    bf16_t* lA0 = As + (wv << 9);
    bf16_t* lA1 = lA0 + 2048;
    bf16_t* lB0 = Bs + (wv << 9);
    bf16_t* lB1 = lB0 + 2048;

    f32x4 acc[4][4];
#pragma unroll
    for (int i = 0; i < 4; i++)
#pragma unroll
        for (int j = 0; j < 4; j++) {
            f32x4 zz = {0.f, 0.f, 0.f, 0.f};
            acc[i][j] = zz;
        }

    const bf16_t* fa = As + (wm * 64 + l16) * 32 + quad * 8;
    const bf16_t* fb = Bs + (wn * 64 + l16) * 32 + quad * 8;

    for (int kt = 0; kt < K; kt += 32) {
        lds16(gA0 + kt, lA0);
        lds16(gA1 + kt, lA1);
        lds16(gB0 + kt, lB0);
        lds16(gB1 + kt, lB1);
        __syncthreads();
        bf16x8 af[4], bfr[4];
#pragma unroll
        for (int i = 0; i < 4; i++) {
            af[i]  = *(const bf16x8*)(fa + i * 512);
            bfr[i] = *(const bf16x8*)(fb + i * 512);
        }
#pragma unroll
        for (int i = 0; i < 4; i++)
#pragma unroll
            for (int j = 0; j < 4; j++)
                acc[i][j] = __builtin_amdgcn_mfma_f32_16x16x32_bf16(
                    af[i], bfr[j], acc[i][j], 0, 0, 0);
        __syncthreads();
    }

    int mbase = m0 + wm * 64 + quad * 4;
    int nbase = n0 + wn * 64 + l16;

    if (outH) {
        bf16_t* oh = outH + (long long)z * strideOz;
#pragma unroll
        for (int i = 0; i < 4; i++)
#pragma unroll
            for (int j = 0; j < 4; j++) {
                int col = nbase + j * 16;
                float bv = bias ? bias[col] : 0.f;
#pragma unroll
                for (int r = 0; r < 4; r++) {
                    int row = mbase + i * 16 + r;
                    float v = acc[i][j][r] + bv;
                    if (gelu_flag)
                        v = 0.5f * v * (1.f + erff(v * 0.70710678118654752f));
                    oh[(size_t)row * N + col] = (bf16_t)v;
                }
            }
    } else {
#pragma unroll
        for (int i = 0; i < 4; i++)
#pragma unroll
            for (int j = 0; j < 4; j++) {
                int col = nbase + j * 16;
                float bv = bias ? bias[col] : 0.f;
#pragma unroll
                for (int r = 0; r < 4; r++) {
                    int row = mbase + i * 16 + r;
                    float v = acc[i][j][r] + bv;
                    if (resid) v += resid[(size_t)row * N + col];
                    outF[(size_t)row * N + col] = v;
                }
            }
        if (pmaxp) {
            int nt = blockIdx.x * 2 + wn;
#pragma unroll
            for (int i = 0; i < 4; i++)
#pragma unroll
                for (int r = 0; r < 4; r++) {
                    int row = mbase + i * 16 + r;
                    float mx = fmaxf(fmaxf(acc[i][0][r], acc[i][1][r]),
                                     fmaxf(acc[i][2][r], acc[i][3][r]));
                    mx = fmaxf(mx, __shfl_xor(mx, 1));
                    mx = fmaxf(mx, __shfl_xor(mx, 2));
                    mx = fmaxf(mx, __shfl_xor(mx, 4));
                    mx = fmaxf(mx, __shfl_xor(mx, 8));
                    float sm = 0.f;
#pragma unroll
                    for (int j = 0; j < 4; j++)
                        sm += __expf(acc[i][j][r] - mx);
                    sm += __shfl_xor(sm, 1);
                    sm += __shfl_xor(sm, 2);
                    sm += __shfl_xor(sm, 4);
                    sm += __shfl_xor(sm, 8);
                    if (l16 == 0) {
                        pmaxp[(size_t)row * nt500 + nt] = mx;
                        psump[(size_t)row * nt500 + nt] = sm;
                    }
                }
        }
    }
}

// ------------------------------------------------------------- attention ----
// MFMA flash attention: 64q x 64k tiles, 4 waves (wave = 16 q-rows), bf16
// MFMA 16x16x32 for QK^T and PV, online softmax fully in registers
// (rows = quad*4+r, reduce over l16 lanes). V staged transposed (Vt[96][72],
// pad 72 keeps ds_read_b128 16B-aligned); P crosses C-layout -> A-frag via
// LDS (Ps[64][72]). LDS total = 47.6 KB -> 3 blocks/CU.
__global__ __launch_bounds__(256) void flash_kernel(
    const bf16_t* __restrict__ Qg, const bf16_t* __restrict__ Kg,
    const bf16_t* __restrict__ Vg, bf16_t* __restrict__ Og)
{
    __shared__ __align__(16) bf16_t Qs[64 * 96];
    __shared__ __align__(16) bf16_t Ks[64 * 96];
    __shared__ __align__(16) bf16_t Vt[96 * 72];   // [d][key], transposed
    __shared__ __align__(16) bf16_t Ps[64 * 72];   // [q][key]

    int qt = blockIdx.x, bh = blockIdx.y;
    int b = bh >> 3, h = bh & 7;
    int tid = threadIdx.x;
    int wv = tid >> 6, lane = tid & 63;
    int quad = lane >> 4, l16 = lane & 15;
    size_t qrow0 = (size_t)b * SEQ + qt * 64;

    // this thread's 3 staging chunks (768 x 16B chunks cover a 64x96 bf16 tile)
    int cr[3], c8[3];
#pragma unroll
    for (int j = 0; j < 3; j++) {
        int c = wv * 192 + j * 64 + lane;
        cr[j] = c / 12;                 // key/q row within tile
        c8[j] = (c - cr[j] * 12) * 8;   // element offset within row
    }

    // stage Q tile -> LDS (linear, matches lds16 lane order)
#pragma unroll
    for (int j = 0; j < 3; j++)
        lds16(Qg + (qrow0 + cr[j]) * EMB + h * HSZ + c8[j],
              Qs + (size_t)(wv * 192 + j * 64) * 8);

    const float scale = 0.10206207261596577f;  // 96^-0.5

    f32x4 o[6];
#pragma unroll
    for (int dt = 0; dt < 6; dt++) { f32x4 z = {0.f, 0.f, 0.f, 0.f}; o[dt] = z; }
    float mrun[4], lrun[4];
#pragma unroll
    for (int r = 0; r < 4; r++) { mrun[r] = -1e30f; lrun[r] = 0.f; }

    bf16x8 qf[3];

    for (int kt = 0; kt <= qt; kt++) {
        size_t krow0 = (size_t)b * SEQ + kt * 64;
        // issue K -> LDS (async) and V -> regs; Ks is free (all QK reads of the
        // previous tile completed before the previous barrier (b))
#pragma unroll
        for (int j = 0; j < 3; j++)
            lds16(Kg + (krow0 + cr[j]) * EMB + h * HSZ + c8[j],
                  Ks + (size_t)(wv * 192 + j * 64) * 8);
        bf16x8 vr[3];
#pragma unroll
        for (int j = 0; j < 3; j++)
            vr[j] = *(const bf16x8*)(Vg + (krow0 + cr[j]) * EMB + h * HSZ + c8[j]);
        __syncthreads();   // (a) drains lds16 (Q+K ready); prev PV Vt reads done

        if (kt == 0) {
#pragma unroll
            for (int ks = 0; ks < 3; ks++)
                qf[ks] = *(const bf16x8*)(Qs + (wv * 16 + l16) * 96 + ks * 32 + quad * 8);
        }

        // write V transposed into Vt[d][key]
#pragma unroll
        for (int j = 0; j < 3; j++)
#pragma unroll
            for (int e = 0; e < 8; e++)
                Vt[(c8[j] + e) * 72 + cr[j]] = vr[j][e];

        // QK^T: wave's 16 q-rows x 64 keys (4 n-tiles x 3 k-slices)
        f32x4 s[4];
#pragma unroll
        for (int nt = 0; nt < 4; nt++) { f32x4 z = {0.f, 0.f, 0.f, 0.f}; s[nt] = z; }
#pragma unroll
        for (int ks = 0; ks < 3; ks++)
#pragma unroll
            for (int nt = 0; nt < 4; nt++) {
                bf16x8 kf = *(const bf16x8*)(Ks + (nt * 16 + l16) * 96 + ks * 32 + quad * 8);
                s[nt] = __builtin_amdgcn_mfma_f32_16x16x32_bf16(qf[ks], kf, s[nt], 0, 0, 0);
            }

        // online softmax (C layout: col = l16 -> key, row = quad*4+r)
        bool diag = (kt == qt);
        float p[4][4];
#pragma unroll
        for (int r = 0; r < 4; r++) {
            float sv[4];
#pragma unroll
            for (int nt = 0; nt < 4; nt++) {
                float v = s[nt][r] * scale;
                if (diag && (nt * 16 + l16 > wv * 16 + quad * 4 + r)) v = -1e30f;
                sv[nt] = v;
            }
            float mx = fmaxf(fmaxf(sv[0], sv[1]), fmaxf(sv[2], sv[3]));
            mx = fmaxf(mx, __shfl_xor(mx, 1));
            mx = fmaxf(mx, __shfl_xor(mx, 2));
            mx = fmaxf(mx, __shfl_xor(mx, 4));
            mx = fmaxf(mx, __shfl_xor(mx, 8));
            float mnew = fmaxf(mrun[r], mx);
            float al = __expf(mrun[r] - mnew);
            float sm = 0.f;
#pragma unroll
            for (int nt = 0; nt < 4; nt++) {
                float pv = __expf(sv[nt] - mnew);
                p[nt][r] = pv;
                sm += pv;
            }
            sm += __shfl_xor(sm, 1);
            sm += __shfl_xor(sm, 2);
            sm += __shfl_xor(sm, 4);
            sm += __shfl_xor(sm, 8);
            lrun[r] = lrun[r] * al + sm;
            mrun[r] = mnew;
#pragma unroll
            for (int dt = 0; dt < 6; dt++) o[dt][r] *= al;
        }

        // P -> LDS (wave-private 16 rows)
#pragma unroll
        for (int nt = 0; nt < 4; nt++)
#pragma unroll
            for (int r = 0; r < 4; r++)
                Ps[(wv * 16 + quad * 4 + r) * 72 + nt * 16 + l16] = (bf16_t)p[nt][r];

        __syncthreads();   // (b) Vt + P visible; all Ks reads complete

        // PV: O[16q x 96d] += P[16q x 64k] @ V[64k x 96d]
#pragma unroll
        for (int ks = 0; ks < 2; ks++) {
            bf16x8 pf = *(const bf16x8*)(Ps + (wv * 16 + l16) * 72 + ks * 32 + quad * 8);
#pragma unroll
            for (int dt = 0; dt < 6; dt++) {
                bf16x8 vf = *(const bf16x8*)(Vt + (dt * 16 + l16) * 72 + ks * 32 + quad * 8);
                o[dt] = __builtin_amdgcn_mfma_f32_16x16x32_bf16(pf, vf, o[dt], 0, 0, 0);
            }
        }
    }

    // epilogue: normalize and store (C layout)
#pragma unroll
    for (int r = 0; r < 4; r++) {
        float inv = 1.f / lrun[r];
        size_t row = qrow0 + wv * 16 + quad * 4 + r;
#pragma unroll
        for (int dt = 0; dt < 6; dt++)
            Og[row * EMB + h * HSZ + dt * 16 + l16] = (bf16_t)(o[dt][r] * inv);
    }
}

// ------------------------------------------------------------------ loss ----
__global__ __launch_bounds__(256) void loss_rows_kernel(
    const float* __restrict__ pmax, const float* __restrict__ psum,
    const float* __restrict__ logits, const int* __restrict__ tgt,
    float* __restrict__ rl)
{
    int row = blockIdx.x, tid = threadIdx.x;
    const float* pm = pmax + (size_t)row * NT500;
    const float* ps = psum + (size_t)row * NT500;
    float mx = -1e30f;
    for (int i = tid; i < NT500; i += 256) mx = fmaxf(mx, pm[i]);
#pragma unroll
    for (int off = 32; off >= 1; off >>= 1) mx = fmaxf(mx, __shfl_xor(mx, off));
    __shared__ float red[8];
    int w = tid >> 6;
    if ((tid & 63) == 0) red[w] = mx;
    __syncthreads();
    mx = fmaxf(fmaxf(red[0], red[1]), fmaxf(red[2], red[3]));
    float sm = 0.f;
    for (int i = tid; i < NT500; i += 256) sm += ps[i] * __expf(pm[i] - mx);
#pragma unroll
    for (int off = 32; off >= 1; off >>= 1) sm += __shfl_xor(sm, off);
    if ((tid & 63) == 0) red[4 + w] = sm;
    __syncthreads();
    if (tid == 0) {
        float tot = red[4] + red[5] + red[6] + red[7];
        float lse = mx + logf(tot);
        float tl = logits[(size_t)row * VOC + tgt[row]];
        rl[row] = lse - tl;
    }
}

__global__ __launch_bounds__(256) void loss_final_kernel(
    const float* __restrict__ rl, float* __restrict__ dst)
{
    int tid = threadIdx.x;
    float s = 0.f;
    for (int i = tid; i < MTOK; i += 256) s += rl[i];
#pragma unroll
    for (int off = 32; off >= 1; off >>= 1) s += __shfl_xor(s, off);
    __shared__ float red[4];
    if ((tid & 63) == 0) red[tid >> 6] = s;
    __syncthreads();
    if (tid == 0)
        dst[0] = (red[0] + red[1] + red[2] + red[3]) * (1.0f / MTOK);
}

// ---------------------------------------------------------------- launch ----
extern "C" void kernel_launch(void* const* d_in, const int* in_sizes, int n_in,
                              void* d_out, int out_size, void* d_ws, size_t ws_size,
                              hipStream_t stream)
{
    (void)in_sizes; (void)n_in;
    const int*   idx  = (const int*)d_in[0];
    const int*   tgt  = (const int*)d_in[1];
    const float* tok  = (const float*)d_in[2];
    const float* pos  = (const float*)d_in[3];
    const float* Wq   = (const float*)d_in[4];
    const float* Wk   = (const float*)d_in[5];
    const float* Wv   = (const float*)d_in[6];
    const float* Wo   = (const float*)d_in[7];
    const float* bo   = (const float*)d_in[8];
    const float* ln1g = (const float*)d_in[9];
    const float* ln1b = (const float*)d_in[10];
    const float* ln2g = (const float*)d_in[11];
    const float* ln2b = (const float*)d_in[12];
    const float* W1   = (const float*)d_in[13];
    const float* b1   = (const float*)d_in[14];
    const float* W2   = (const float*)d_in[15];
    const float* b2   = (const float*)d_in[16];
    const float* lnfg = (const float*)d_in[17];
    const float* lnfb = (const float*)d_in[18];
    float* logits = (float*)d_out;

    char* ws = (char*)d_ws;
    constexpr size_t EE  = (size_t)EMB * EMB;        // 589824
    constexpr size_t ACT = (size_t)MTOK * EMB;       // 3145728 elems
    constexpr size_t EF  = (size_t)EMB * FFDIM;      // 2359296

    // ws layout (bytes)
    float*  Xf    = (float*) (ws + 0);                // 12,582,912
    bf16_t* LnO   = (bf16_t*)(ws + 12582912);         //  6,291,456
    bf16_t* QKV   = (bf16_t*)(ws + 18874368);         // 18,874,368 (3x)
    bf16_t* AtO   = (bf16_t*)(ws + 37748736);         //  6,291,456
    bf16_t* Ffh   = (bf16_t*)(ws + 44040192);         // 25,165,824
    bf16_t* WqkvT = (bf16_t*)(ws + 69206016);         // 28,311,552
    bf16_t* WoT   = (bf16_t*)(ws + 97517568);         //  9,437,184
    bf16_t* W1T   = (bf16_t*)(ws + 106954752);        // 37,748,736
    bf16_t* W2T   = (bf16_t*)(ws + 144703488);        // 37,748,736
    bf16_t* EmbB  = (bf16_t*)(ws + 182452224);        // 49,152,000
    float*  Pmax  = (float*) (ws + 231604224);        //  8,192,000
    float*  Psum  = (float*) (ws + 239796224);        //  8,192,000
    float*  Rloss = (float*) (ws + 247988224);        //     16,384
    if (ws_size < (size_t)248004608) return;          // need ~248 MB scratch

    dim3 tb(32, 8);
    // weight/emb cast+transpose (per call; inputs are restored every launch)
    cast_bf16_kernel<<<24000, 256, 0, stream>>>(tok, EmbB, (VOC * EMB) / 4);
    transpose_cast_kernel<<<dim3(24, 24, 8), tb, 0, stream>>>(
        Wq, WqkvT + 0 * EE, EMB, EMB, (long long)EE, (long long)(3 * EE));
    transpose_cast_kernel<<<dim3(24, 24, 8), tb, 0, stream>>>(
        Wk, WqkvT + 1 * EE, EMB, EMB, (long long)EE, (long long)(3 * EE));
    transpose_cast_kernel<<<dim3(24, 24, 8), tb, 0, stream>>>(
        Wv, WqkvT + 2 * EE, EMB, EMB, (long long)EE, (long long)(3 * EE));
    transpose_cast_kernel<<<dim3(24, 24, 8), tb, 0, stream>>>(
        Wo, WoT, EMB, EMB, (long long)EE, (long long)EE);
    transpose_cast_kernel<<<dim3(96, 24, 8), tb, 0, stream>>>(
        W1, W1T, EMB, FFDIM, (long long)EF, (long long)EF);
    transpose_cast_kernel<<<dim3(24, 96, 8), tb, 0, stream>>>(
        W2, W2T, FFDIM, EMB, (long long)EF, (long long)EF);

    embed_kernel<<<MTOK, 256, 0, stream>>>(idx, tok, pos, Xf);

    for (int l = 0; l < LNUM; l++) {
        ln_kernel<<<MTOK, 256, 0, stream>>>(Xf, ln1g + l * EMB, ln1b + l * EMB, LnO);
        // q,k,v (z-batched, no bias, bf16 out)
        gemm_nt_kernel<<<dim3(6, 32, 3), 256, 0, stream>>>(
            LnO, WqkvT + (size_t)l * 3 * EE, EMB, EMB,
            (long long)EE, (long long)ACT,
            nullptr, nullptr, nullptr, QKV, 0, nullptr, nullptr, 0);
        flash_kernel<<<dim3(16, 32), 256, 0, stream>>>(
            QKV, QKV + ACT, QKV + 2 * ACT, AtO);
        // attn proj + bias + residual -> x (f32, in place)
        gemm_nt_kernel<<<dim3(6, 32, 1), 256, 0, stream>>>(
            AtO, WoT + (size_t)l * EE, EMB, EMB, 0, 0,
            bo + l * EMB, Xf, Xf, nullptr, 0, nullptr, nullptr, 0);
        ln_kernel<<<MTOK, 256, 0, stream>>>(Xf, ln2g + l * EMB, ln2b + l * EMB, LnO);
        // fc1 + bias + gelu -> bf16
        gemm_nt_kernel<<<dim3(24, 32, 1), 256, 0, stream>>>(
            LnO, W1T + (size_t)l * EF, FFDIM, EMB, 0, 0,
            b1 + l * FFDIM, nullptr, nullptr, Ffh, 1, nullptr, nullptr, 0);
        // fc2 + bias + residual -> x
        gemm_nt_kernel<<<dim3(6, 32, 1), 256, 0, stream>>>(
            Ffh, W2T + (size_t)l * EF, EMB, FFDIM, 0, 0,
            b2 + l * EMB, Xf, Xf, nullptr, 0, nullptr, nullptr, 0);
    }

    ln_kernel<<<MTOK, 256, 0, stream>>>(Xf, lnfg, lnfb, LnO);
    // lm head (tied, NT vs tok_emb) + fused per-64-col softmax partials
    gemm_nt_kernel<<<dim3(250, 32, 1), 256, 0, stream>>>(
        LnO, EmbB, VOC, EMB, 0, 0,
        nullptr, nullptr, logits, nullptr, 0, Pmax, Psum, NT500);
    loss_rows_kernel<<<MTOK, 256, 0, stream>>>(Pmax, Psum, logits, tgt, Rloss);
    loss_final_kernel<<<1, 256, 0, stream>>>(Rloss, logits + ((size_t)out_size - 1));
}

// Round 3
// 3213.870 us; speedup vs baseline: 1.1562x; 1.1562x over previous
//
#include <hip/hip_runtime.h>
#include <cstdint>
#include <cstddef>

// ---------------------------------------------------------------------------
// MiniGPT forward (L=8, H=8, E=768, FF=3072, V=32000, B=4, T=1024) on gfx950.
// Residual stream fp32; all GEMMs bf16 MFMA (16x16x32) NT form.
// This revision: gemm_nt pipelined (double-buffered LDS, counted vmcnt(4),
// raw s_barrier — no full drain per K-step) + lm-head grid m-fastest so the
// 49 MB B matrix stays cache-resident instead of streaming 32x.
// ---------------------------------------------------------------------------

typedef __bf16 bf16_t;
typedef __bf16 bf16x8 __attribute__((ext_vector_type(8)));
typedef __bf16 bf16x4 __attribute__((ext_vector_type(4)));
typedef float  f32x4  __attribute__((ext_vector_type(4)));

#define LNUM 8
#define EMB 768
#define FFDIM 3072
#define HEADS 8
#define HSZ 96
#define VOC 32000
#define SEQ 1024
#define MTOK 4096          // B*T
#define NT500 500          // VOC/64 partial tiles per row

__device__ __forceinline__ void lds16(const void* g, void* l) {
    __builtin_amdgcn_global_load_lds(
        (__attribute__((address_space(1))) void*)(g),
        (__attribute__((address_space(3))) void*)(l), 16, 0, 0);
}

// ---------------------------------------------------------------- casts ----
__global__ __launch_bounds__(256) void cast_bf16_kernel(
    const float* __restrict__ s, bf16_t* __restrict__ d, int n4)
{
    int i = blockIdx.x * 256 + threadIdx.x;
    if (i < n4) {
        float4 v = ((const float4*)s)[i];
        bf16x4 o;
        o[0] = (bf16_t)v.x; o[1] = (bf16_t)v.y;
        o[2] = (bf16_t)v.z; o[3] = (bf16_t)v.w;
        ((bf16x4*)d)[i] = o;
    }
}

// src [K,N] f32 (batched)  ->  dst [N,K] bf16 (batched)
__global__ __launch_bounds__(256) void transpose_cast_kernel(
    const float* __restrict__ src, bf16_t* __restrict__ dst,
    int K, int N, long long sstride, long long dstride)
{
    __shared__ float t[32][33];
    src += (long long)blockIdx.z * sstride;
    dst += (long long)blockIdx.z * dstride;
    int n0 = blockIdx.x * 32, k0 = blockIdx.y * 32;
    int tx = threadIdx.x, ty = threadIdx.y;
    for (int i = ty; i < 32; i += 8)
        t[i][tx] = src[(size_t)(k0 + i) * N + n0 + tx];
    __syncthreads();
    for (int i = ty; i < 32; i += 8)
        dst[(size_t)(n0 + i) * K + k0 + tx] = (bf16_t)t[tx][i];
}

// ---------------------------------------------------------------- embed ----
__global__ __launch_bounds__(256) void embed_kernel(
    const int* __restrict__ idx, const float* __restrict__ tok,
    const float* __restrict__ pos, float* __restrict__ x)
{
    int row = blockIdx.x, tid = threadIdx.x;
    int id = idx[row];
    int t = row & (SEQ - 1);
    const float* te = tok + (size_t)id * EMB;
    const float* pe = pos + (size_t)t * EMB;
    float* xr = x + (size_t)row * EMB;
    xr[tid]       = te[tid]       + pe[tid];
    xr[tid + 256] = te[tid + 256] + pe[tid + 256];
    xr[tid + 512] = te[tid + 512] + pe[tid + 512];
}

// ------------------------------------------------------------- layernorm ----
__global__ __launch_bounds__(256) void ln_kernel(
    const float* __restrict__ x, const float* __restrict__ g,
    const float* __restrict__ bb, bf16_t* __restrict__ out)
{
    int row = blockIdx.x, tid = threadIdx.x;
    const float* xr = x + (size_t)row * EMB;
    float v0 = xr[tid], v1 = xr[tid + 256], v2 = xr[tid + 512];
    float s = v0 + v1 + v2;
    float s2 = v0 * v0 + v1 * v1 + v2 * v2;
#pragma unroll
    for (int off = 32; off >= 1; off >>= 1) {
        s  += __shfl_xor(s, off);
        s2 += __shfl_xor(s2, off);
    }
    __shared__ float red[8];
    int w = tid >> 6;
    if ((tid & 63) == 0) { red[w] = s; red[4 + w] = s2; }
    __syncthreads();
    s  = red[0] + red[1] + red[2] + red[3];
    s2 = red[4] + red[5] + red[6] + red[7];
    float mean = s * (1.0f / EMB);
    float var  = s2 * (1.0f / EMB) - mean * mean;
    float rs = rsqrtf(var + 1e-5f);
    bf16_t* orow = out + (size_t)row * EMB;
    orow[tid]       = (bf16_t)((v0 - mean) * rs * g[tid]       + bb[tid]);
    orow[tid + 256] = (bf16_t)((v1 - mean) * rs * g[tid + 256] + bb[tid + 256]);
    orow[tid + 512] = (bf16_t)((v2 - mean) * rs * g[tid + 512] + bb[tid + 512]);
}

// ------------------------------------------------------------------ GEMM ----
// C[M,N] = A[M,K](bf16) @ B[N,K](bf16)^T  (NT, both K-contiguous).
// 128x128 tile, BK=32, 256 threads = 4 waves (2x2 of 64x64), 16 MFMAs/wave/iter.
// Double-buffered LDS; tile t+2 staged (async global_load_lds) right after the
// post-compute barrier; counted s_waitcnt vmcnt(4) waits only for the tile
// about to be consumed (never a full drain in the main loop).
// mfirst: m0 from blockIdx.x (lm-head: keeps 49MB B cache-resident).
// outH!=null: bf16 out (+bias, +gelu). else f32 out (+bias, +residual, +lm partials).
__global__ __launch_bounds__(256) void gemm_nt_kernel(
    const bf16_t* __restrict__ A, const bf16_t* __restrict__ B,
    int N, int K, long long strideBz, long long strideOz,
    const float* __restrict__ bias, const float* __restrict__ resid,
    float* __restrict__ outF, bf16_t* __restrict__ outH, int gelu_flag,
    float* __restrict__ pmaxp, float* __restrict__ psump, int nt500, int mfirst)
{
    __shared__ __align__(16) bf16_t As[2 * 128 * 32];
    __shared__ __align__(16) bf16_t Bs[2 * 128 * 32];
    int tid = threadIdx.x;
    int m0, n0, ntcol;
    if (mfirst) { m0 = blockIdx.x * 128; n0 = blockIdx.y * 128; ntcol = blockIdx.y; }
    else        { n0 = blockIdx.x * 128; m0 = blockIdx.y * 128; ntcol = blockIdx.x; }
    int z = blockIdx.z;
    B += (long long)z * strideBz;

    int wv = tid >> 6, lane = tid & 63;
    int quad = lane >> 4, l16 = lane & 15;
    int wm = wv >> 1, wn = wv & 1;

    const bf16_t* gA0 = A + (size_t)(m0 + (tid >> 2)) * K + (tid & 3) * 8;
    const bf16_t* gA1 = gA0 + (size_t)64 * K;
    const bf16_t* gB0 = B + (size_t)(n0 + (tid >> 2)) * K + (tid & 3) * 8;
    const bf16_t* gB1 = gB0 + (size_t)64 * K;

    f32x4 acc[4][4];
#pragma unroll
    for (int i = 0; i < 4; i++)
#pragma unroll
        for (int j = 0; j < 4; j++) {
            f32x4 zz = {0.f, 0.f, 0.f, 0.f};
            acc[i][j] = zz;
        }

    const bf16_t* fa = As + (wm * 64 + l16) * 32 + quad * 8;
    const bf16_t* fb = Bs + (wn * 64 + l16) * 32 + quad * 8;

    // stage K-step kt into buffer bb (4 lds16 per thread = vmcnt +4 per wave)
    auto stage = [&](int bb, int kt) {
        bf16_t* dA = As + (bb << 12) + (wv << 9);
        bf16_t* dB = Bs + (bb << 12) + (wv << 9);
        lds16(gA0 + kt, dA);
        lds16(gA1 + kt, dA + 2048);
        lds16(gB0 + kt, dB);
        lds16(gB1 + kt, dB + 2048);
    };
    auto compute = [&](int bb) {
        const bf16_t* fa_c = fa + (bb << 12);
        const bf16_t* fb_c = fb + (bb << 12);
        bf16x8 af[4], bfr[4];
#pragma unroll
        for (int i = 0; i < 4; i++) {
            af[i]  = *(const bf16x8*)(fa_c + i * 512);
            bfr[i] = *(const bf16x8*)(fb_c + i * 512);
        }
#pragma unroll
        for (int i = 0; i < 4; i++)
#pragma unroll
            for (int j = 0; j < 4; j++)
                acc[i][j] = __builtin_amdgcn_mfma_f32_16x16x32_bf16(
                    af[i], bfr[j], acc[i][j], 0, 0, 0);
    };

    int nsteps = K >> 5;                    // K/32 (24 or 96)
    stage(0, 0);
    if (nsteps > 1) stage(1, 32);
    for (int t = 0; t < nsteps - 1; ++t) {
        int cur = t & 1;
        asm volatile("s_waitcnt vmcnt(4)" ::: "memory");   // tile t staged
        __builtin_amdgcn_s_barrier();
        __builtin_amdgcn_sched_barrier(0);
        compute(cur);
        __builtin_amdgcn_sched_barrier(0);
        __builtin_amdgcn_s_barrier();                      // all reads of cur done
        if (t + 2 < nsteps) stage(cur, (t + 2) << 5);
    }
    {
        int cur = (nsteps - 1) & 1;
        asm volatile("s_waitcnt vmcnt(0)" ::: "memory");   // last tile staged
        __builtin_amdgcn_s_barrier();
        __builtin_amdgcn_sched_barrier(0);
        compute(cur);
    }

    int mbase = m0 + wm * 64 + quad * 4;
    int nbase = n0 + wn * 64 + l16;

    if (outH) {
        bf16_t* oh = outH + (long long)z * strideOz;
#pragma unroll
        for (int i = 0; i < 4; i++)
#pragma unroll
            for (int j = 0; j < 4; j++) {
                int col = nbase + j * 16;
                float bv = bias ? bias[col] : 0.f;
#pragma unroll
                for (int r = 0; r < 4; r++) {
                    int row = mbase + i * 16 + r;
                    float v = acc[i][j][r] + bv;
                    if (gelu_flag)
                        v = 0.5f * v * (1.f + erff(v * 0.70710678118654752f));
                    oh[(size_t)row * N + col] = (bf16_t)v;
                }
            }
    } else {
#pragma unroll
        for (int i = 0; i < 4; i++)
#pragma unroll
            for (int j = 0; j < 4; j++) {
                int col = nbase + j * 16;
                float bv = bias ? bias[col] : 0.f;
#pragma unroll
                for (int r = 0; r < 4; r++) {
                    int row = mbase + i * 16 + r;
                    float v = acc[i][j][r] + bv;
                    if (resid) v += resid[(size_t)row * N + col];
                    outF[(size_t)row * N + col] = v;
                }
            }
        if (pmaxp) {
            int nt = ntcol * 2 + wn;
#pragma unroll
            for (int i = 0; i < 4; i++)
#pragma unroll
                for (int r = 0; r < 4; r++) {
                    int row = mbase + i * 16 + r;
                    float mx = fmaxf(fmaxf(acc[i][0][r], acc[i][1][r]),
                                     fmaxf(acc[i][2][r], acc[i][3][r]));
                    mx = fmaxf(mx, __shfl_xor(mx, 1));
                    mx = fmaxf(mx, __shfl_xor(mx, 2));
                    mx = fmaxf(mx, __shfl_xor(mx, 4));
                    mx = fmaxf(mx, __shfl_xor(mx, 8));
                    float sm = 0.f;
#pragma unroll
                    for (int j = 0; j < 4; j++)
                        sm += __expf(acc[i][j][r] - mx);
                    sm += __shfl_xor(sm, 1);
                    sm += __shfl_xor(sm, 2);
                    sm += __shfl_xor(sm, 4);
                    sm += __shfl_xor(sm, 8);
                    if (l16 == 0) {
                        pmaxp[(size_t)row * nt500 + nt] = mx;
                        psump[(size_t)row * nt500 + nt] = sm;
                    }
                }
        }
    }
}

// ------------------------------------------------------------- attention ----
// MFMA flash attention: 64q x 64k tiles, 4 waves (wave = 16 q-rows), bf16
// MFMA 16x16x32 for QK^T and PV, online softmax fully in registers
// (rows = quad*4+r, reduce over l16 lanes). V staged transposed (Vt[96][72],
// pad 72 keeps ds_read_b128 16B-aligned); P crosses C-layout -> A-frag via
// LDS (Ps[64][72]). LDS total = 47.6 KB -> 3 blocks/CU.
__global__ __launch_bounds__(256) void flash_kernel(
    const bf16_t* __restrict__ Qg, const bf16_t* __restrict__ Kg,
    const bf16_t* __restrict__ Vg, bf16_t* __restrict__ Og)
{
    __shared__ __align__(16) bf16_t Qs[64 * 96];
    __shared__ __align__(16) bf16_t Ks[64 * 96];
    __shared__ __align__(16) bf16_t Vt[96 * 72];   // [d][key], transposed
    __shared__ __align__(16) bf16_t Ps[64 * 72];   // [q][key]

    int qt = blockIdx.x, bh = blockIdx.y;
    int b = bh >> 3, h = bh & 7;
    int tid = threadIdx.x;
    int wv = tid >> 6, lane = tid & 63;
    int quad = lane >> 4, l16 = lane & 15;
    size_t qrow0 = (size_t)b * SEQ + qt * 64;

    // this thread's 3 staging chunks (768 x 16B chunks cover a 64x96 bf16 tile)
    int cr[3], c8[3];
#pragma unroll
    for (int j = 0; j < 3; j++) {
        int c = wv * 192 + j * 64 + lane;
        cr[j] = c / 12;                 // key/q row within tile
        c8[j] = (c - cr[j] * 12) * 8;   // element offset within row
    }

    // stage Q tile -> LDS (linear, matches lds16 lane order)
#pragma unroll
    for (int j = 0; j < 3; j++)
        lds16(Qg + (qrow0 + cr[j]) * EMB + h * HSZ + c8[j],
              Qs + (size_t)(wv * 192 + j * 64) * 8);

    const float scale = 0.10206207261596577f;  // 96^-0.5

    f32x4 o[6];
#pragma unroll
    for (int dt = 0; dt < 6; dt++) { f32x4 z = {0.f, 0.f, 0.f, 0.f}; o[dt] = z; }
    float mrun[4], lrun[4];
#pragma unroll
    for (int r = 0; r < 4; r++) { mrun[r] = -1e30f; lrun[r] = 0.f; }

    bf16x8 qf[3];

    for (int kt = 0; kt <= qt; kt++) {
        size_t krow0 = (size_t)b * SEQ + kt * 64;
        // issue K -> LDS (async) and V -> regs; Ks is free (all QK reads of the
        // previous tile completed before the previous barrier (b))
#pragma unroll
        for (int j = 0; j < 3; j++)
            lds16(Kg + (krow0 + cr[j]) * EMB + h * HSZ + c8[j],
                  Ks + (size_t)(wv * 192 + j * 64) * 8);
        bf16x8 vr[3];
#pragma unroll
        for (int j = 0; j < 3; j++)
            vr[j] = *(const bf16x8*)(Vg + (krow0 + cr[j]) * EMB + h * HSZ + c8[j]);
        __syncthreads();   // (a) drains lds16 (Q+K ready); prev PV Vt reads done

        if (kt == 0) {
#pragma unroll
            for (int ks = 0; ks < 3; ks++)
                qf[ks] = *(const bf16x8*)(Qs + (wv * 16 + l16) * 96 + ks * 32 + quad * 8);
        }

        // write V transposed into Vt[d][key]
#pragma unroll
        for (int j = 0; j < 3; j++)
#pragma unroll
            for (int e = 0; e < 8; e++)
                Vt[(c8[j] + e) * 72 + cr[j]] = vr[j][e];

        // QK^T: wave's 16 q-rows x 64 keys (4 n-tiles x 3 k-slices)
        f32x4 s[4];
#pragma unroll
        for (int nt = 0; nt < 4; nt++) { f32x4 z = {0.f, 0.f, 0.f, 0.f}; s[nt] = z; }
#pragma unroll
        for (int ks = 0; ks < 3; ks++)
#pragma unroll
            for (int nt = 0; nt < 4; nt++) {
                bf16x8 kf = *(const bf16x8*)(Ks + (nt * 16 + l16) * 96 + ks * 32 + quad * 8);
                s[nt] = __builtin_amdgcn_mfma_f32_16x16x32_bf16(qf[ks], kf, s[nt], 0, 0, 0);
            }

        // online softmax (C layout: col = l16 -> key, row = quad*4+r)
        bool diag = (kt == qt);
        float p[4][4];
#pragma unroll
        for (int r = 0; r < 4; r++) {
            float sv[4];
#pragma unroll
            for (int nt = 0; nt < 4; nt++) {
                float v = s[nt][r] * scale;
                if (diag && (nt * 16 + l16 > wv * 16 + quad * 4 + r)) v = -1e30f;
                sv[nt] = v;
            }
            float mx = fmaxf(fmaxf(sv[0], sv[1]), fmaxf(sv[2], sv[3]));
            mx = fmaxf(mx, __shfl_xor(mx, 1));
            mx = fmaxf(mx, __shfl_xor(mx, 2));
            mx = fmaxf(mx, __shfl_xor(mx, 4));
            mx = fmaxf(mx, __shfl_xor(mx, 8));
            float mnew = fmaxf(mrun[r], mx);
            float al = __expf(mrun[r] - mnew);
            float sm = 0.f;
#pragma unroll
            for (int nt = 0; nt < 4; nt++) {
                float pv = __expf(sv[nt] - mnew);
                p[nt][r] = pv;
                sm += pv;
            }
            sm += __shfl_xor(sm, 1);
            sm += __shfl_xor(sm, 2);
            sm += __shfl_xor(sm, 4);
            sm += __shfl_xor(sm, 8);
            lrun[r] = lrun[r] * al + sm;
            mrun[r] = mnew;
#pragma unroll
            for (int dt = 0; dt < 6; dt++) o[dt][r] *= al;
        }

        // P -> LDS (wave-private 16 rows)
#pragma unroll
        for (int nt = 0; nt < 4; nt++)
#pragma unroll
            for (int r = 0; r < 4; r++)
                Ps[(wv * 16 + quad * 4 + r) * 72 + nt * 16 + l16] = (bf16_t)p[nt][r];

        __syncthreads();   // (b) Vt + P visible; all Ks reads complete

        // PV: O[16q x 96d] += P[16q x 64k] @ V[64k x 96d]
#pragma unroll
        for (int ks = 0; ks < 2; ks++) {
            bf16x8 pf = *(const bf16x8*)(Ps + (wv * 16 + l16) * 72 + ks * 32 + quad * 8);
#pragma unroll
            for (int dt = 0; dt < 6; dt++) {
                bf16x8 vf = *(const bf16x8*)(Vt + (dt * 16 + l16) * 72 + ks * 32 + quad * 8);
                o[dt] = __builtin_amdgcn_mfma_f32_16x16x32_bf16(pf, vf, o[dt], 0, 0, 0);
            }
        }
    }

    // epilogue: normalize and store (C layout)
#pragma unroll
    for (int r = 0; r < 4; r++) {
        float inv = 1.f / lrun[r];
        size_t row = qrow0 + wv * 16 + quad * 4 + r;
#pragma unroll
        for (int dt = 0; dt < 6; dt++)
            Og[row * EMB + h * HSZ + dt * 16 + l16] = (bf16_t)(o[dt][r] * inv);
    }
}

// ------------------------------------------------------------------ loss ----
__global__ __launch_bounds__(256) void loss_rows_kernel(
    const float* __restrict__ pmax, const float* __restrict__ psum,
    const float* __restrict__ logits, const int* __restrict__ tgt,
    float* __restrict__ rl)
{
    int row = blockIdx.x, tid = threadIdx.x;
    const float* pm = pmax + (size_t)row * NT500;
    const float* ps = psum + (size_t)row * NT500;
    float mx = -1e30f;
    for (int i = tid; i < NT500; i += 256) mx = fmaxf(mx, pm[i]);
#pragma unroll
    for (int off = 32; off >= 1; off >>= 1) mx = fmaxf(mx, __shfl_xor(mx, off));
    __shared__ float red[8];
    int w = tid >> 6;
    if ((tid & 63) == 0) red[w] = mx;
    __syncthreads();
    mx = fmaxf(fmaxf(red[0], red[1]), fmaxf(red[2], red[3]));
    float sm = 0.f;
    for (int i = tid; i < NT500; i += 256) sm += ps[i] * __expf(pm[i] - mx);
#pragma unroll
    for (int off = 32; off >= 1; off >>= 1) sm += __shfl_xor(sm, off);
    if ((tid & 63) == 0) red[4 + w] = sm;
    __syncthreads();
    if (tid == 0) {
        float tot = red[4] + red[5] + red[6] + red[7];
        float lse = mx + logf(tot);
        float tl = logits[(size_t)row * VOC + tgt[row]];
        rl[row] = lse - tl;
    }
}

__global__ __launch_bounds__(256) void loss_final_kernel(
    const float* __restrict__ rl, float* __restrict__ dst)
{
    int tid = threadIdx.x;
    float s = 0.f;
    for (int i = tid; i < MTOK; i += 256) s += rl[i];
#pragma unroll
    for (int off = 32; off >= 1; off >>= 1) s += __shfl_xor(s, off);
    __shared__ float red[4];
    if ((tid & 63) == 0) red[tid >> 6] = s;
    __syncthreads();
    if (tid == 0)
        dst[0] = (red[0] + red[1] + red[2] + red[3]) * (1.0f / MTOK);
}

// ---------------------------------------------------------------- launch ----
extern "C" void kernel_launch(void* const* d_in, const int* in_sizes, int n_in,
                              void* d_out, int out_size, void* d_ws, size_t ws_size,
                              hipStream_t stream)
{
    (void)in_sizes; (void)n_in;
    const int*   idx  = (const int*)d_in[0];
    const int*   tgt  = (const int*)d_in[1];
    const float* tok  = (const float*)d_in[2];
    const float* pos  = (const float*)d_in[3];
    const float* Wq   = (const float*)d_in[4];
    const float* Wk   = (const float*)d_in[5];
    const float* Wv   = (const float*)d_in[6];
    const float* Wo   = (const float*)d_in[7];
    const float* bo   = (const float*)d_in[8];
    const float* ln1g = (const float*)d_in[9];
    const float* ln1b = (const float*)d_in[10];
    const float* ln2g = (const float*)d_in[11];
    const float* ln2b = (const float*)d_in[12];
    const float* W1   = (const float*)d_in[13];
    const float* b1   = (const float*)d_in[14];
    const float* W2   = (const float*)d_in[15];
    const float* b2   = (const float*)d_in[16];
    const float* lnfg = (const float*)d_in[17];
    const float* lnfb = (const float*)d_in[18];
    float* logits = (float*)d_out;

    char* ws = (char*)d_ws;
    constexpr size_t EE  = (size_t)EMB * EMB;        // 589824
    constexpr size_t ACT = (size_t)MTOK * EMB;       // 3145728 elems
    constexpr size_t EF  = (size_t)EMB * FFDIM;      // 2359296

    // ws layout (bytes)
    float*  Xf    = (float*) (ws + 0);                // 12,582,912
    bf16_t* LnO   = (bf16_t*)(ws + 12582912);         //  6,291,456
    bf16_t* QKV   = (bf16_t*)(ws + 18874368);         // 18,874,368 (3x)
    bf16_t* AtO   = (bf16_t*)(ws + 37748736);         //  6,291,456
    bf16_t* Ffh   = (bf16_t*)(ws + 44040192);         // 25,165,824
    bf16_t* WqkvT = (bf16_t*)(ws + 69206016);         // 28,311,552
    bf16_t* WoT   = (bf16_t*)(ws + 97517568);         //  9,437,184
    bf16_t* W1T   = (bf16_t*)(ws + 106954752);        // 37,748,736
    bf16_t* W2T   = (bf16_t*)(ws + 144703488);        // 37,748,736
    bf16_t* EmbB  = (bf16_t*)(ws + 182452224);        // 49,152,000
    float*  Pmax  = (float*) (ws + 231604224);        //  8,192,000
    float*  Psum  = (float*) (ws + 239796224);        //  8,192,000
    float*  Rloss = (float*) (ws + 247988224);        //     16,384
    if (ws_size < (size_t)248004608) return;          // need ~248 MB scratch

    dim3 tb(32, 8);
    // weight/emb cast+transpose (per call; inputs are restored every launch)
    cast_bf16_kernel<<<24000, 256, 0, stream>>>(tok, EmbB, (VOC * EMB) / 4);
    transpose_cast_kernel<<<dim3(24, 24, 8), tb, 0, stream>>>(
        Wq, WqkvT + 0 * EE, EMB, EMB, (long long)EE, (long long)(3 * EE));
    transpose_cast_kernel<<<dim3(24, 24, 8), tb, 0, stream>>>(
        Wk, WqkvT + 1 * EE, EMB, EMB, (long long)EE, (long long)(3 * EE));
    transpose_cast_kernel<<<dim3(24, 24, 8), tb, 0, stream>>>(
        Wv, WqkvT + 2 * EE, EMB, EMB, (long long)EE, (long long)(3 * EE));
    transpose_cast_kernel<<<dim3(24, 24, 8), tb, 0, stream>>>(
        Wo, WoT, EMB, EMB, (long long)EE, (long long)EE);
    transpose_cast_kernel<<<dim3(96, 24, 8), tb, 0, stream>>>(
        W1, W1T, EMB, FFDIM, (long long)EF, (long long)EF);
    transpose_cast_kernel<<<dim3(24, 96, 8), tb, 0, stream>>>(
        W2, W2T, FFDIM, EMB, (long long)EF, (long long)EF);

    embed_kernel<<<MTOK, 256, 0, stream>>>(idx, tok, pos, Xf);

    for (int l = 0; l < LNUM; l++) {
        ln_kernel<<<MTOK, 256, 0, stream>>>(Xf, ln1g + l * EMB, ln1b + l * EMB, LnO);
        // q,k,v (z-batched, no bias, bf16 out)
        gemm_nt_kernel<<<dim3(6, 32, 3), 256, 0, stream>>>(
            LnO, WqkvT + (size_t)l * 3 * EE, EMB, EMB,
            (long long)EE, (long long)ACT,
            nullptr, nullptr, nullptr, QKV, 0, nullptr, nullptr, 0, 0);
        flash_kernel<<<dim3(16, 32), 256, 0, stream>>>(
            QKV, QKV + ACT, QKV + 2 * ACT, AtO);
        // attn proj + bias + residual -> x (f32, in place)
        gemm_nt_kernel<<<dim3(6, 32, 1), 256, 0, stream>>>(
            AtO, WoT + (size_t)l * EE, EMB, EMB, 0, 0,
            bo + l * EMB, Xf, Xf, nullptr, 0, nullptr, nullptr, 0, 0);
        ln_kernel<<<MTOK, 256, 0, stream>>>(Xf, ln2g + l * EMB, ln2b + l * EMB, LnO);
        // fc1 + bias + gelu -> bf16
        gemm_nt_kernel<<<dim3(24, 32, 1), 256, 0, stream>>>(
            LnO, W1T + (size_t)l * EF, FFDIM, EMB, 0, 0,
            b1 + l * FFDIM, nullptr, nullptr, Ffh, 1, nullptr, nullptr, 0, 0);
        // fc2 + bias + residual -> x
        gemm_nt_kernel<<<dim3(6, 32, 1), 256, 0, stream>>>(
            Ffh, W2T + (size_t)l * EF, EMB, FFDIM, 0, 0,
            b2 + l * EMB, Xf, Xf, nullptr, 0, nullptr, nullptr, 0, 0);
    }

    ln_kernel<<<MTOK, 256, 0, stream>>>(Xf, lnfg, lnfb, LnO);
    // lm head (tied, NT vs tok_emb) + fused per-64-col softmax partials
    // m-fastest grid: consecutive blocks share the B panel -> B fetched ~once
    gemm_nt_kernel<<<dim3(32, 250, 1), 256, 0, stream>>>(
        LnO, EmbB, VOC, EMB, 0, 0,
        nullptr, nullptr, logits, nullptr, 0, Pmax, Psum, NT500, 1);
    loss_rows_kernel<<<MTOK, 256, 0, stream>>>(Pmax, Psum, logits, tgt, Rloss);
    loss_final_kernel<<<1, 256, 0, stream>>>(Rloss, logits + ((size_t)out_size - 1));
}